// Round 1
// baseline (11509.230 us; speedup 1.0000x reference)
//
#include <hip/hip_runtime.h>

#define NTOK 49
#define DIM 256
#define HEADS 8
#define HD 32
#define NWM 64
#define SCALE 0.17677669529663687f

// ---------------------------------------------------------------------------
// K1: fused qkv projection + windowed multi-head attention.
// One block per window (4096 blocks, 256 threads).
// Thread t: token row n = t&63 (49 active), channel-quarter jq = t>>6.
// Writes attention output (pre-proj), layout [bw][n][h*32+d], into `ao`
// (which is d_out used as scratch; K2 overwrites it in place).
// ---------------------------------------------------------------------------
__global__ __launch_bounds__(256) void k1_attn(
    const float* __restrict__ x,          // [4096,49,256]
    const float* __restrict__ mask,       // [64,49,49]
    const float* __restrict__ qkv_w,      // [768,256]
    const float* __restrict__ qkv_b,      // [768]
    const float* __restrict__ bias_table, // [169,8]
    const int*   __restrict__ rel_idx,    // [49*49]
    float* __restrict__ ao)               // [4096,49,256]
{
    __shared__ float qh[NTOK][HD + 1];
    __shared__ float kh[NTOK][HD + 1];
    __shared__ float vh[NTOK][HD + 1];
    __shared__ float S_s[NTOK][52];
    __shared__ float bias_s[NTOK][52];
    __shared__ float mask_s[NTOK][52];

    const int t  = threadIdx.x;
    const int bw = blockIdx.x;
    const int n  = t & 63;
    const int jq = t >> 6;
    const bool act = (n < NTOK);

    // stage the per-image shift mask once (window-in-image = bw % 64)
    const float* mw = mask + (size_t)(bw & (NWM - 1)) * NTOK * NTOK;
    for (int o = t; o < NTOK * NTOK; o += 256)
        mask_s[o / NTOK][o % NTOK] = mw[o];

    const float* xrow = x + ((size_t)bw * NTOK + n) * DIM;

    for (int h = 0; h < HEADS; ++h) {
        __syncthreads();  // previous head fully consumed bias_s / qh/kh/vh

        // relative-position bias gather for this head
        for (int o = t; o < NTOK * NTOK; o += 256)
            bias_s[o / NTOK][o % NTOK] = bias_table[rel_idx[o] * HEADS + h];

        // qkv for this head: thread computes 24 of the 96 head channels for
        // its token row. Weight rows are wave-uniform (jq constant per wave).
        if (act) {
            float acc[24];
            #pragma unroll
            for (int j = 0; j < 24; ++j) acc[j] = 0.f;

            for (int k0 = 0; k0 < DIM; k0 += 32) {
                float4 xr[8];
                #pragma unroll
                for (int kk = 0; kk < 8; ++kk)
                    xr[kk] = ((const float4*)(xrow + k0))[kk];
                #pragma unroll
                for (int j = 0; j < 24; ++j) {
                    const int c96 = jq * 24 + j;
                    const int s = c96 >> 5, d = c96 & 31;
                    const float4* wrow =
                        (const float4*)(qkv_w + (size_t)(s * DIM + h * HD + d) * DIM + k0);
                    #pragma unroll
                    for (int k4 = 0; k4 < 8; ++k4) {
                        float4 w4 = wrow[k4];
                        acc[j] += xr[k4].x * w4.x + xr[k4].y * w4.y +
                                  xr[k4].z * w4.z + xr[k4].w * w4.w;
                    }
                }
            }
            #pragma unroll
            for (int j = 0; j < 24; ++j) {
                const int c96 = jq * 24 + j;
                const int s = c96 >> 5, d = c96 & 31;
                const int ch = s * DIM + h * HD + d;
                float v = acc[j] + qkv_b[ch];
                if (s == 0)      qh[n][d] = v * SCALE;
                else if (s == 1) kh[n][d] = v;
                else             vh[n][d] = v;
            }
        }
        __syncthreads();

        // S = q @ k^T + bias + mask
        for (int o = t; o < NTOK * NTOK; o += 256) {
            const int i = o / NTOK, m = o % NTOK;
            float acc = 0.f;
            #pragma unroll
            for (int d = 0; d < HD; ++d) acc += qh[i][d] * kh[m][d];
            S_s[i][m] = acc + bias_s[i][m] + mask_s[i][m];
        }
        __syncthreads();

        // row softmax (one thread per row; 49 rows)
        if (t < NTOK) {
            float mx = -1e30f;
            for (int m = 0; m < NTOK; ++m) mx = fmaxf(mx, S_s[t][m]);
            float sum = 0.f;
            for (int m = 0; m < NTOK; ++m) {
                float e = __expf(S_s[t][m] - mx);
                S_s[t][m] = e;
                sum += e;
            }
            const float inv = 1.f / sum;
            for (int m = 0; m < NTOK; ++m) S_s[t][m] *= inv;
        }
        __syncthreads();

        // ao = P @ v   -> global, channel c = h*32 + d
        for (int o = t; o < NTOK * HD; o += 256) {
            const int i = o / HD, d = o % HD;
            float acc = 0.f;
            for (int m = 0; m < NTOK; ++m) acc += S_s[i][m] * vh[m][d];
            ao[((size_t)bw * NTOK + i) * DIM + h * HD + d] = acc;
        }
    }
}

// ---------------------------------------------------------------------------
// K2: output projection, in place on d_out.
// 64 rows per block; rows staged to LDS BEFORE any write (in-place safe).
// Thread t: row r = t&63, output column quarter cq = t>>6 (64 cols).
// proj_w loads are wave-uniform; row data read from LDS.
// ---------------------------------------------------------------------------
__global__ __launch_bounds__(256) void k2_proj(
    const float* __restrict__ pw,   // [256,256]
    const float* __restrict__ pb,   // [256]
    float* __restrict__ io)         // [200704,256] in-place
{
    extern __shared__ float rows_s[];  // [64][260]

    const int t  = threadIdx.x;
    const int r  = t & 63;
    const int cq = t >> 6;
    const float* src = io + (size_t)blockIdx.x * 64 * DIM;

    // cooperative coalesced load of the 64 input rows
    for (int i = t; i < 64 * (DIM / 4); i += 256) {
        const int rr = i >> 6, k4 = i & 63;
        *((float4*)&rows_s[rr * 260 + k4 * 4]) = ((const float4*)src)[i];
    }
    __syncthreads();

    float acc[64];
    #pragma unroll
    for (int j = 0; j < 64; ++j) acc[j] = pb[cq * 64 + j];

    for (int k0 = 0; k0 < DIM; k0 += 16) {
        float4 xr[4];
        #pragma unroll
        for (int kk = 0; kk < 4; ++kk)
            xr[kk] = *((const float4*)&rows_s[r * 260 + k0 + kk * 4]);
        #pragma unroll
        for (int j = 0; j < 64; ++j) {
            const float4* wrow = (const float4*)(pw + (size_t)(cq * 64 + j) * DIM + k0);
            #pragma unroll
            for (int k4 = 0; k4 < 4; ++k4) {
                float4 w4 = wrow[k4];
                acc[j] += xr[k4].x * w4.x + xr[k4].y * w4.y +
                          xr[k4].z * w4.z + xr[k4].w * w4.w;
            }
        }
    }

    float* dst = io + ((size_t)blockIdx.x * 64 + r) * DIM + cq * 64;
    #pragma unroll
    for (int j4 = 0; j4 < 16; ++j4) {
        float4 v = make_float4(acc[j4 * 4 + 0], acc[j4 * 4 + 1],
                               acc[j4 * 4 + 2], acc[j4 * 4 + 3]);
        ((float4*)dst)[j4] = v;
    }
}

extern "C" void kernel_launch(void* const* d_in, const int* in_sizes, int n_in,
                              void* d_out, int out_size, void* d_ws, size_t ws_size,
                              hipStream_t stream) {
    const float* x    = (const float*)d_in[0];
    const float* mask = (const float*)d_in[1];
    const float* qkvw = (const float*)d_in[2];
    const float* qkvb = (const float*)d_in[3];
    const float* pw   = (const float*)d_in[4];
    const float* pb   = (const float*)d_in[5];
    const float* bt   = (const float*)d_in[6];
    const int*   ri   = (const int*)d_in[7];
    float* out = (float*)d_out;

    const int nwin = in_sizes[0] / (NTOK * DIM);   // 4096

    k1_attn<<<nwin, 256, 0, stream>>>(x, mask, qkvw, qkvb, bt, ri, out);
    k2_proj<<<(nwin * NTOK) / 64, 256, 64 * 260 * sizeof(float), stream>>>(pw, pb, out);
}

// Round 2
// 918.005 us; speedup vs baseline: 12.5372x; 12.5372x over previous
//
#include <hip/hip_runtime.h>
#include <hip/hip_bf16.h>

#define NTOK 49
#define DIM 256
#define HEADS 8
#define HD 32
#define SCALE 0.17677669529663687f

typedef float f32x4 __attribute__((ext_vector_type(4)));
typedef short bf16x8 __attribute__((ext_vector_type(8)));

__device__ __forceinline__ unsigned short f2bf(float f) {
    union { __hip_bfloat16 h; unsigned short u; } c;
    c.h = __float2bfloat16(f);
    return c.u;
}

// ---------------------------------------------------------------------------
// K0: one-time prep into d_ws:
//   wq  [768*256]  bf16   (qkv_w converted)
//   wp  [256*256]  bf16   (proj_w converted)
//   bmall [64][8][49*49] f32 : mask[w,i,j] + bias_table[rel_idx[i,j], h]
// ---------------------------------------------------------------------------
__global__ void k0_prep(const float* __restrict__ qkv_w, const float* __restrict__ proj_w,
                        const float* __restrict__ mask, const float* __restrict__ bias_table,
                        const int* __restrict__ rel_idx,
                        unsigned short* __restrict__ wq, unsigned short* __restrict__ wp,
                        float* __restrict__ bmall, int total)
{
    int i = blockIdx.x * 256 + threadIdx.x;
    if (i >= total) return;
    if (i < 196608) {
        wq[i] = f2bf(qkv_w[i]);
    } else if (i < 262144) {
        wp[i - 196608] = f2bf(proj_w[i - 196608]);
    } else {
        int u = i - 262144;                 // [0, 64*8*2401)
        int w = u / 19208, rem = u % 19208; // 19208 = 8*2401
        int h = rem / 2401, ij = rem % 2401;
        bmall[u] = mask[w * 2401 + ij] + bias_table[rel_idx[ij] * HEADS + h];
    }
}

// ---------------------------------------------------------------------------
// K1: fused qkv + attention per window. 4096 blocks x 256 threads (4 waves).
// MFMA 16x16x32 bf16 throughout. Writes pre-proj attnout (fp32) to d_out.
// Fragment layouts (gfx950): A: row=l&15, k=(l>>4)*8+j (16B contig)
//                            B: col=l&15, k=(l>>4)*8+j (16B contig)
//                            D: col=l&15, row=(l>>4)*4+j
// ---------------------------------------------------------------------------
__global__ __launch_bounds__(256) void k1_attn(
    const float* __restrict__ x,            // [4096,49,256] f32
    const float* __restrict__ qkv_b,        // [768] f32
    const unsigned short* __restrict__ wq,  // [768,256] bf16
    const float* __restrict__ bmall,        // [64,8,2401] f32
    float* __restrict__ ao)                 // [4096,49,256] f32 (pre-proj)
{
    __shared__ unsigned short xs[64 * 256];   // x bf16, swizzled, 32768 B
    __shared__ unsigned short qs[64 * 40];    // q bf16 [tok][ch], pitch 40
    __shared__ unsigned short ksh[64 * 40];   // k bf16 [tok][ch], pitch 40
    __shared__ unsigned short vts[32 * 72];   // v^T bf16 [ch][tok], pitch 72
    __shared__ unsigned short ps[64 * 64];    // P bf16, swizzled, pitch 64

    const int t = threadIdx.x;
    const int bw = blockIdx.x;
    const int lane = t & 63;
    const int wv = t >> 6;           // wave 0..3
    const int l15 = lane & 15, l16 = lane >> 4;
    const int mg = wv >> 1, ng = wv & 1;

    // ---- stage x -> bf16 LDS (XOR swizzle on 16B chunks), zero-pad rows >=49
    const float* xw = x + (size_t)bw * NTOK * DIM;
    for (int cidx = t; cidx < 2048; cidx += 256) {
        int row = cidx >> 5, c8 = cidx & 31;
        int dst = row * 256 + ((c8 * 8) ^ ((row & 7) << 3));
        bf16x8 v;
        if (row < NTOK) {
            float4 a = *(const float4*)(xw + row * DIM + c8 * 8);
            float4 b = *(const float4*)(xw + row * DIM + c8 * 8 + 4);
            v[0] = (short)f2bf(a.x); v[1] = (short)f2bf(a.y);
            v[2] = (short)f2bf(a.z); v[3] = (short)f2bf(a.w);
            v[4] = (short)f2bf(b.x); v[5] = (short)f2bf(b.y);
            v[6] = (short)f2bf(b.z); v[7] = (short)f2bf(b.w);
        } else {
            v = (bf16x8){0,0,0,0,0,0,0,0};
        }
        *(bf16x8*)(xs + dst) = v;
    }

    const float* bmh_base = bmall + (size_t)(bw & 63) * 8 * 2401;

    for (int h = 0; h < HEADS; ++h) {
        __syncthreads();   // barrier A: prev head's S/PV reads done

        // ---------- qkv GEMM: wave = (mg,ng); 2 M-tiles x 3 N-tiles ----------
        f32x4 acc[2][3];
        #pragma unroll
        for (int mt = 0; mt < 2; ++mt)
            #pragma unroll
            for (int tt = 0; tt < 3; ++tt) acc[mt][tt] = (f32x4){0.f,0.f,0.f,0.f};

        const unsigned short* bptr[3];
        int seg_[3], ch_[3];
        #pragma unroll
        for (int tt = 0; tt < 3; ++tt) {
            int n = (ng * 3 + tt) * 16 + l15;      // 0..95
            int seg = n >> 5, ch = n & 31;
            seg_[tt] = seg; ch_[tt] = ch;
            bptr[tt] = wq + (size_t)(seg * 256 + h * HD + ch) * 256 + l16 * 8;
        }
        int arow[2];
        #pragma unroll
        for (int mt = 0; mt < 2; ++mt) arow[mt] = (mg * 2 + mt) * 16 + l15;

        #pragma unroll
        for (int ks2 = 0; ks2 < 8; ++ks2) {
            bf16x8 a[2], b[3];
            #pragma unroll
            for (int mt = 0; mt < 2; ++mt)
                a[mt] = *(const bf16x8*)(xs + arow[mt] * 256 +
                          ((ks2 * 32 + l16 * 8) ^ ((arow[mt] & 7) << 3)));
            #pragma unroll
            for (int tt = 0; tt < 3; ++tt)
                b[tt] = *(const bf16x8*)(bptr[tt] + ks2 * 32);
            #pragma unroll
            for (int mt = 0; mt < 2; ++mt)
                #pragma unroll
                for (int tt = 0; tt < 3; ++tt)
                    acc[mt][tt] = __builtin_amdgcn_mfma_f32_16x16x32_bf16(
                        a[mt], b[tt], acc[mt][tt], 0, 0, 0);
        }

        // store q (scaled), k row-major [tok][ch]; v transposed [ch][tok]
        #pragma unroll
        for (int tt = 0; tt < 3; ++tt) {
            int seg = seg_[tt], ch = ch_[tt];
            float bias = qkv_b[seg * 256 + h * HD + ch];
            #pragma unroll
            for (int mt = 0; mt < 2; ++mt) {
                int r0 = (mg * 2 + mt) * 16 + l16 * 4;
                if (seg == 2) {
                    unsigned int lo = (unsigned)f2bf(acc[mt][tt][0] + bias) |
                                      ((unsigned)f2bf(acc[mt][tt][1] + bias) << 16);
                    unsigned int hi = (unsigned)f2bf(acc[mt][tt][2] + bias) |
                                      ((unsigned)f2bf(acc[mt][tt][3] + bias) << 16);
                    *(uint2*)(vts + ch * 72 + r0) = make_uint2(lo, hi);
                } else if (seg == 0) {
                    #pragma unroll
                    for (int j = 0; j < 4; ++j)
                        qs[(r0 + j) * 40 + ch] = f2bf((acc[mt][tt][j] + bias) * SCALE);
                } else {
                    #pragma unroll
                    for (int j = 0; j < 4; ++j)
                        ksh[(r0 + j) * 40 + ch] = f2bf(acc[mt][tt][j] + bias);
                }
            }
        }
        __syncthreads();   // barrier B: q/k/vT ready

        // ---------- S = q k^T : wave owns M-tile wv (rows 16wv..16wv+15) -----
        bf16x8 aq = *(const bf16x8*)(qs + (wv * 16 + l15) * 40 + l16 * 8);
        f32x4 s[4];
        #pragma unroll
        for (int nt = 0; nt < 4; ++nt) {
            bf16x8 bk = *(const bf16x8*)(ksh + (nt * 16 + l15) * 40 + l16 * 8);
            f32x4 z = (f32x4){0.f,0.f,0.f,0.f};
            s[nt] = __builtin_amdgcn_mfma_f32_16x16x32_bf16(aq, bk, z, 0, 0, 0);
        }

        // ---------- in-register softmax (row r in 16 lanes, 4 rows/lane) ----
        const float* bmh = bmh_base + h * 2401;
        int rbase = wv * 16 + l16 * 4;
        #pragma unroll
        for (int j = 0; j < 4; ++j) {
            int r = rbase + j;
            float mx = -1e30f;
            #pragma unroll
            for (int nt = 0; nt < 4; ++nt) {
                int c = nt * 16 + l15;
                float v = s[nt][j];
                if (c < NTOK) { if (r < NTOK) v += bmh[r * NTOK + c]; }
                else v = -1e30f;
                s[nt][j] = v;
                mx = fmaxf(mx, v);
            }
            #pragma unroll
            for (int msk = 1; msk <= 8; msk <<= 1)
                mx = fmaxf(mx, __shfl_xor(mx, msk));
            float sum = 0.f;
            #pragma unroll
            for (int nt = 0; nt < 4; ++nt) {
                float e = __expf(s[nt][j] - mx);
                s[nt][j] = e;
                sum += e;
            }
            #pragma unroll
            for (int msk = 1; msk <= 8; msk <<= 1)
                sum += __shfl_xor(sum, msk);
            float inv = 1.f / sum;
            #pragma unroll
            for (int nt = 0; nt < 4; ++nt) {
                int c = nt * 16 + l15;
                ps[r * 64 + (c ^ ((r & 7) << 3))] = f2bf(s[nt][j] * inv);
            }
        }
        __syncthreads();   // barrier C: P ready

        // ---------- out = P @ v : wave owns M-tile wv, 2 N-tiles (32 ch) ----
        f32x4 o[2] = {(f32x4){0.f,0.f,0.f,0.f}, (f32x4){0.f,0.f,0.f,0.f}};
        int prow = wv * 16 + l15;
        #pragma unroll
        for (int kt = 0; kt < 2; ++kt) {
            bf16x8 ap = *(const bf16x8*)(ps + prow * 64 +
                          ((kt * 32 + l16 * 8) ^ ((prow & 7) << 3)));
            #pragma unroll
            for (int nt = 0; nt < 2; ++nt) {
                bf16x8 bv = *(const bf16x8*)(vts + (nt * 16 + l15) * 72 +
                                             kt * 32 + l16 * 8);
                o[nt] = __builtin_amdgcn_mfma_f32_16x16x32_bf16(ap, bv, o[nt], 0, 0, 0);
            }
        }
        int r0 = wv * 16 + l16 * 4;
        #pragma unroll
        for (int nt = 0; nt < 2; ++nt) {
            int chh = nt * 16 + l15;
            #pragma unroll
            for (int j = 0; j < 4; ++j) {
                int tok = r0 + j;
                if (tok < NTOK)
                    ao[((size_t)bw * NTOK + tok) * DIM + h * HD + chh] = o[nt][j];
            }
        }
    }
}

// ---------------------------------------------------------------------------
// K2: output projection, in place on d_out (stage 64 rows first). MFMA bf16.
// 3136 blocks x 256 threads. wave=(mg,ng): 2 M-tiles x 8 N-tiles.
// ---------------------------------------------------------------------------
__global__ __launch_bounds__(256) void k2_proj(
    const unsigned short* __restrict__ wp,  // [256,256] bf16
    const float* __restrict__ pb,           // [256]
    float* __restrict__ io)                 // [200704,256] in-place
{
    __shared__ unsigned short as_[64 * 256];

    const int t = threadIdx.x;
    const int lane = t & 63;
    const int wv = t >> 6;
    const int l15 = lane & 15, l16 = lane >> 4;
    const int mg = wv >> 1, ng = wv & 1;

    const float* src = io + (size_t)blockIdx.x * 64 * DIM;
    for (int cidx = t; cidx < 2048; cidx += 256) {
        int row = cidx >> 5, c8 = cidx & 31;
        float4 a = *(const float4*)(src + row * DIM + c8 * 8);
        float4 b = *(const float4*)(src + row * DIM + c8 * 8 + 4);
        bf16x8 v;
        v[0] = (short)f2bf(a.x); v[1] = (short)f2bf(a.y);
        v[2] = (short)f2bf(a.z); v[3] = (short)f2bf(a.w);
        v[4] = (short)f2bf(b.x); v[5] = (short)f2bf(b.y);
        v[6] = (short)f2bf(b.z); v[7] = (short)f2bf(b.w);
        *(bf16x8*)(as_ + row * 256 + ((c8 * 8) ^ ((row & 7) << 3))) = v;
    }
    __syncthreads();

    f32x4 acc[2][8];
    #pragma unroll
    for (int mt = 0; mt < 2; ++mt)
        #pragma unroll
        for (int nt = 0; nt < 8; ++nt) acc[mt][nt] = (f32x4){0.f,0.f,0.f,0.f};

    const unsigned short* bbase[8];
    #pragma unroll
    for (int nt = 0; nt < 8; ++nt) {
        int n = ng * 128 + nt * 16 + l15;
        bbase[nt] = wp + (size_t)n * 256 + l16 * 8;
    }
    int arow[2];
    #pragma unroll
    for (int mt = 0; mt < 2; ++mt) arow[mt] = (mg * 2 + mt) * 16 + l15;

    #pragma unroll
    for (int ks2 = 0; ks2 < 8; ++ks2) {
        bf16x8 a[2];
        #pragma unroll
        for (int mt = 0; mt < 2; ++mt)
            a[mt] = *(const bf16x8*)(as_ + arow[mt] * 256 +
                      ((ks2 * 32 + l16 * 8) ^ ((arow[mt] & 7) << 3)));
        #pragma unroll
        for (int nt = 0; nt < 8; ++nt) {
            bf16x8 b = *(const bf16x8*)(bbase[nt] + ks2 * 32);
            #pragma unroll
            for (int mt = 0; mt < 2; ++mt)
                acc[mt][nt] = __builtin_amdgcn_mfma_f32_16x16x32_bf16(
                    a[mt], b, acc[mt][nt], 0, 0, 0);
        }
    }

    #pragma unroll
    for (int nt = 0; nt < 8; ++nt) {
        int col = ng * 128 + nt * 16 + l15;
        float bias = pb[col];
        #pragma unroll
        for (int mt = 0; mt < 2; ++mt) {
            int r0 = (mg * 2 + mt) * 16 + l16 * 4;
            #pragma unroll
            for (int j = 0; j < 4; ++j)
                io[((size_t)blockIdx.x * 64 + r0 + j) * DIM + col] =
                    acc[mt][nt][j] + bias;
        }
    }
}

extern "C" void kernel_launch(void* const* d_in, const int* in_sizes, int n_in,
                              void* d_out, int out_size, void* d_ws, size_t ws_size,
                              hipStream_t stream) {
    const float* x    = (const float*)d_in[0];
    const float* mask = (const float*)d_in[1];
    const float* qkvw = (const float*)d_in[2];
    const float* qkvb = (const float*)d_in[3];
    const float* pw   = (const float*)d_in[4];
    const float* pb   = (const float*)d_in[5];
    const float* bt   = (const float*)d_in[6];
    const int*   ri   = (const int*)d_in[7];
    float* out = (float*)d_out;

    unsigned short* wq = (unsigned short*)d_ws;
    unsigned short* wp = wq + 196608;
    float* bmall = (float*)((char*)d_ws + 524288);

    const int nwin = in_sizes[0] / (NTOK * DIM);   // 4096
    const int total = 262144 + 64 * HEADS * 2401;  // 1491456

    k0_prep<<<(total + 255) / 256, 256, 0, stream>>>(qkvw, pw, mask, bt, ri,
                                                     wq, wp, bmall, total);
    k1_attn<<<nwin, 256, 0, stream>>>(x, qkvb, wq, bmall, out);
    k2_proj<<<(nwin * NTOK) / 64, 256, 0, stream>>>(wp, pb, out);
}

// Round 3
// 488.249 us; speedup vs baseline: 23.5725x; 1.8802x over previous
//
#include <hip/hip_runtime.h>
#include <hip/hip_bf16.h>

#define NTOK 49
#define DIM 256
#define HEADS 8
#define HD 32
#define SCALE 0.17677669529663687f

typedef float f32x4 __attribute__((ext_vector_type(4)));
typedef short bf16x8 __attribute__((ext_vector_type(8)));

__device__ __forceinline__ unsigned short f2bf(float f) {
    union { __hip_bfloat16 h; unsigned short u; } c;
    c.h = __float2bfloat16(f);
    return c.u;
}

// ---------------------------------------------------------------------------
// K0: one-time prep into d_ws:
//   wqf [196608] bf16 : qkv_w shuffled into MFMA B-fragment order
//       idx = ((((h*2+ng)*3+tt)*8+ks2)*64+lane)*8+j
//       -> qkv_w[(seg*256 + h*32 + ch)*256 + ks2*32 + (lane>>4)*8 + j]
//          where n96=(ng*3+tt)*16+(lane&15), seg=n96>>5, ch=n96&31
//   wpf [65536] bf16  : proj_w shuffled likewise
//       idx = (((ng*8+nt)*8+ks2)*64+lane)*8+j
//       -> proj_w[(ng*128+nt*16+(lane&15))*256 + ks2*32 + (lane>>4)*8 + j]
//   bmall [64][8][49*49] f32 : mask[w,i,j] + bias_table[rel_idx[i,j], h]
// ---------------------------------------------------------------------------
__global__ void k0_prep(const float* __restrict__ qkv_w, const float* __restrict__ proj_w,
                        const float* __restrict__ mask, const float* __restrict__ bias_table,
                        const int* __restrict__ rel_idx,
                        unsigned short* __restrict__ wqf, unsigned short* __restrict__ wpf,
                        float* __restrict__ bmall, int total)
{
    int i = blockIdx.x * 256 + threadIdx.x;
    if (i >= total) return;
    if (i < 196608) {
        int j = i & 7, q = i >> 3;
        int lane = q & 63; q >>= 6;
        int ks2 = q & 7;  q >>= 3;
        int tt = q % 3;   q /= 3;
        int ng = q & 1;
        int h  = q >> 1;
        int n96 = (ng * 3 + tt) * 16 + (lane & 15);
        int seg = n96 >> 5, ch = n96 & 31;
        int srow = seg * 256 + h * HD + ch;
        int scol = ks2 * 32 + (lane >> 4) * 8 + j;
        wqf[i] = f2bf(qkv_w[srow * 256 + scol]);
    } else if (i < 262144) {
        int u = i - 196608;
        int j = u & 7, q = u >> 3;
        int lane = q & 63; q >>= 6;
        int ks2 = q & 7;  q >>= 3;
        int nt = q & 7;
        int ng = q >> 3;
        int n = ng * 128 + nt * 16 + (lane & 15);
        int scol = ks2 * 32 + (lane >> 4) * 8 + j;
        wpf[u] = f2bf(proj_w[n * 256 + scol]);
    } else {
        int u = i - 262144;                 // [0, 64*8*2401)
        int w = u / 19208, rem = u % 19208; // 19208 = 8*2401
        int h = rem / 2401, ij = rem % 2401;
        bmall[u] = mask[w * 2401 + ij] + bias_table[rel_idx[ij] * HEADS + h];
    }
}

// ---------------------------------------------------------------------------
// K1: fused qkv + attention per window. 4096 blocks x 256 threads (4 waves).
// LDS = 54272 B -> 3 blocks/CU. All weight B-frags are coalesced 1KiB loads.
// ---------------------------------------------------------------------------
__global__ __launch_bounds__(256, 3) void k1_attn(
    const float* __restrict__ x,             // [4096,49,256] f32
    const float* __restrict__ qkv_b,         // [768] f32
    const unsigned short* __restrict__ wqf,  // fragment-ordered qkv_w bf16
    const float* __restrict__ bmall,         // [64,8,2401] f32
    float* __restrict__ ao)                  // [4096,49,256] f32 (pre-proj)
{
    __shared__ unsigned short xs[64 * 256];   // 32768 B, swizzled
    __shared__ unsigned short qs[64 * 40];    //  5120 B
    __shared__ unsigned short ksh[64 * 40];   //  5120 B
    __shared__ unsigned short vts[32 * 72];   //  4608 B
    __shared__ unsigned short ps[52 * 64];    //  6656 B (rows 0..51 only)

    const int t = threadIdx.x;
    const int bw = blockIdx.x;
    const int lane = t & 63;
    const int wv = t >> 6;
    const int l15 = lane & 15, l16 = lane >> 4;
    const int mg = wv >> 1, ng = wv & 1;

    // ---- stage x -> bf16 LDS (XOR swizzle on 16B chunks), zero-pad rows >=49
    const float* xw = x + (size_t)bw * NTOK * DIM;
    for (int cidx = t; cidx < 2048; cidx += 256) {
        int row = cidx >> 5, c8 = cidx & 31;
        int dst = row * 256 + ((c8 * 8) ^ ((row & 7) << 3));
        bf16x8 v;
        if (row < NTOK) {
            float4 a = *(const float4*)(xw + row * DIM + c8 * 8);
            float4 b = *(const float4*)(xw + row * DIM + c8 * 8 + 4);
            v[0] = (short)f2bf(a.x); v[1] = (short)f2bf(a.y);
            v[2] = (short)f2bf(a.z); v[3] = (short)f2bf(a.w);
            v[4] = (short)f2bf(b.x); v[5] = (short)f2bf(b.y);
            v[6] = (short)f2bf(b.z); v[7] = (short)f2bf(b.w);
        } else {
            v = (bf16x8){0,0,0,0,0,0,0,0};
        }
        *(bf16x8*)(xs + dst) = v;
    }

    const float* bmh_base = bmall + (size_t)(bw & 63) * 8 * 2401;
    const int rb = wv * 16 + l16 * 4;      // softmax row base for this lane
    int arow[2];
    #pragma unroll
    for (int mt = 0; mt < 2; ++mt) arow[mt] = (mg * 2 + mt) * 16 + l15;

    for (int h = 0; h < HEADS; ++h) {
        __syncthreads();   // barrier A: prev head's S/PV consumption done

        // ---- prefetch bias+mask for this lane's softmax rows (hidden by qkv)
        const float* bmh = bmh_base + h * 2401;
        float bm[4][4];
        #pragma unroll
        for (int j = 0; j < 4; ++j) {
            int r = rb + j;
            #pragma unroll
            for (int nt = 0; nt < 4; ++nt) {
                int c = nt * 16 + l15;
                bm[j][nt] = (r < NTOK && c < NTOK) ? bmh[r * NTOK + c] : 0.f;
            }
        }

        // ---------- qkv GEMM: wave = (mg,ng); 2 M-tiles x 3 N-tiles ----------
        f32x4 acc[2][3];
        #pragma unroll
        for (int mt = 0; mt < 2; ++mt)
            #pragma unroll
            for (int tt = 0; tt < 3; ++tt) acc[mt][tt] = (f32x4){0.f,0.f,0.f,0.f};

        const unsigned short* wb = wqf + ((size_t)(h * 2 + ng) * 24) * 512;

        #pragma unroll
        for (int ks2 = 0; ks2 < 8; ++ks2) {
            bf16x8 a[2], b[3];
            #pragma unroll
            for (int mt = 0; mt < 2; ++mt)
                a[mt] = *(const bf16x8*)(xs + arow[mt] * 256 +
                          ((ks2 * 32 + l16 * 8) ^ ((arow[mt] & 7) << 3)));
            #pragma unroll
            for (int tt = 0; tt < 3; ++tt)
                b[tt] = *(const bf16x8*)(wb + (tt * 8 + ks2) * 512 + lane * 8);
            #pragma unroll
            for (int mt = 0; mt < 2; ++mt)
                #pragma unroll
                for (int tt = 0; tt < 3; ++tt)
                    acc[mt][tt] = __builtin_amdgcn_mfma_f32_16x16x32_bf16(
                        a[mt], b[tt], acc[mt][tt], 0, 0, 0);
        }

        // store q (scaled), k row-major [tok][ch]; v transposed [ch][tok]
        #pragma unroll
        for (int tt = 0; tt < 3; ++tt) {
            int n96 = (ng * 3 + tt) * 16 + l15;
            int seg = n96 >> 5, ch = n96 & 31;
            float bias = qkv_b[seg * 256 + h * HD + ch];
            #pragma unroll
            for (int mt = 0; mt < 2; ++mt) {
                int r0 = (mg * 2 + mt) * 16 + l16 * 4;
                if (seg == 2) {
                    unsigned int lo = (unsigned)f2bf(acc[mt][tt][0] + bias) |
                                      ((unsigned)f2bf(acc[mt][tt][1] + bias) << 16);
                    unsigned int hi = (unsigned)f2bf(acc[mt][tt][2] + bias) |
                                      ((unsigned)f2bf(acc[mt][tt][3] + bias) << 16);
                    *(uint2*)(vts + ch * 72 + r0) = make_uint2(lo, hi);
                } else if (seg == 0) {
                    #pragma unroll
                    for (int j = 0; j < 4; ++j)
                        qs[(r0 + j) * 40 + ch] = f2bf((acc[mt][tt][j] + bias) * SCALE);
                } else {
                    #pragma unroll
                    for (int j = 0; j < 4; ++j)
                        ksh[(r0 + j) * 40 + ch] = f2bf(acc[mt][tt][j] + bias);
                }
            }
        }
        __syncthreads();   // barrier B: q/k/vT ready (also drains bm loads)

        // ---------- S = q k^T : wave owns M-tile wv ----------
        bf16x8 aq = *(const bf16x8*)(qs + (wv * 16 + l15) * 40 + l16 * 8);
        f32x4 s[4];
        #pragma unroll
        for (int nt = 0; nt < 4; ++nt) {
            bf16x8 bk = *(const bf16x8*)(ksh + (nt * 16 + l15) * 40 + l16 * 8);
            f32x4 z = (f32x4){0.f,0.f,0.f,0.f};
            s[nt] = __builtin_amdgcn_mfma_f32_16x16x32_bf16(aq, bk, z, 0, 0, 0);
        }

        // ---------- in-register softmax (rows rb..rb+3, cols in 16 lanes) ---
        #pragma unroll
        for (int j = 0; j < 4; ++j) {
            int r = rb + j;
            float mx = -1e30f;
            #pragma unroll
            for (int nt = 0; nt < 4; ++nt) {
                int c = nt * 16 + l15;
                float v = s[nt][j] + bm[j][nt];
                if (c >= NTOK) v = -1e30f;
                s[nt][j] = v;
                mx = fmaxf(mx, v);
            }
            #pragma unroll
            for (int msk = 1; msk <= 8; msk <<= 1)
                mx = fmaxf(mx, __shfl_xor(mx, msk));
            float sum = 0.f;
            #pragma unroll
            for (int nt = 0; nt < 4; ++nt) {
                float e = __expf(s[nt][j] - mx);
                s[nt][j] = e;
                sum += e;
            }
            #pragma unroll
            for (int msk = 1; msk <= 8; msk <<= 1)
                sum += __shfl_xor(sum, msk);
            float inv = 1.f / sum;
            if (r < 52) {
                #pragma unroll
                for (int nt = 0; nt < 4; ++nt) {
                    int c = nt * 16 + l15;
                    ps[r * 64 + (c ^ ((r & 7) << 3))] = f2bf(s[nt][j] * inv);
                }
            }
        }
        __syncthreads();   // barrier C: P ready

        // ---------- out = P @ v : wave owns M-tile wv, 2 N-tiles ----------
        f32x4 o[2] = {(f32x4){0.f,0.f,0.f,0.f}, (f32x4){0.f,0.f,0.f,0.f}};
        int prow = wv * 16 + l15;
        if (prow > 48) prow = 48;   // rows >=49 produce discarded outputs
        #pragma unroll
        for (int kt = 0; kt < 2; ++kt) {
            bf16x8 ap = *(const bf16x8*)(ps + prow * 64 +
                          ((kt * 32 + l16 * 8) ^ ((prow & 7) << 3)));
            #pragma unroll
            for (int nt = 0; nt < 2; ++nt) {
                bf16x8 bv = *(const bf16x8*)(vts + (nt * 16 + l15) * 72 +
                                             kt * 32 + l16 * 8);
                o[nt] = __builtin_amdgcn_mfma_f32_16x16x32_bf16(ap, bv, o[nt], 0, 0, 0);
            }
        }
        int r0 = wv * 16 + l16 * 4;
        #pragma unroll
        for (int nt = 0; nt < 2; ++nt) {
            int chh = nt * 16 + l15;
            #pragma unroll
            for (int j = 0; j < 4; ++j) {
                int tok = r0 + j;
                if (tok < NTOK)
                    ao[((size_t)bw * NTOK + tok) * DIM + h * HD + chh] = o[nt][j];
            }
        }
    }
}

// ---------------------------------------------------------------------------
// K2: output projection, in place on d_out (stage 64 rows first). MFMA bf16.
// ---------------------------------------------------------------------------
__global__ __launch_bounds__(256, 3) void k2_proj(
    const unsigned short* __restrict__ wpf,  // fragment-ordered proj_w bf16
    const float* __restrict__ pb,            // [256]
    float* __restrict__ io)                  // [200704,256] in-place
{
    __shared__ unsigned short as_[64 * 256];

    const int t = threadIdx.x;
    const int lane = t & 63;
    const int wv = t >> 6;
    const int l15 = lane & 15, l16 = lane >> 4;
    const int mg = wv >> 1, ng = wv & 1;

    const float* src = io + (size_t)blockIdx.x * 64 * DIM;
    for (int cidx = t; cidx < 2048; cidx += 256) {
        int row = cidx >> 5, c8 = cidx & 31;
        float4 a = *(const float4*)(src + row * DIM + c8 * 8);
        float4 b = *(const float4*)(src + row * DIM + c8 * 8 + 4);
        bf16x8 v;
        v[0] = (short)f2bf(a.x); v[1] = (short)f2bf(a.y);
        v[2] = (short)f2bf(a.z); v[3] = (short)f2bf(a.w);
        v[4] = (short)f2bf(b.x); v[5] = (short)f2bf(b.y);
        v[6] = (short)f2bf(b.z); v[7] = (short)f2bf(b.w);
        *(bf16x8*)(as_ + row * 256 + ((c8 * 8) ^ ((row & 7) << 3))) = v;
    }
    __syncthreads();

    f32x4 acc[2][8];
    #pragma unroll
    for (int mt = 0; mt < 2; ++mt)
        #pragma unroll
        for (int nt = 0; nt < 8; ++nt) acc[mt][nt] = (f32x4){0.f,0.f,0.f,0.f};

    int arow[2];
    #pragma unroll
    for (int mt = 0; mt < 2; ++mt) arow[mt] = (mg * 2 + mt) * 16 + l15;

    const unsigned short* wb = wpf + (size_t)ng * 8 * 8 * 512;

    #pragma unroll
    for (int ks2 = 0; ks2 < 8; ++ks2) {
        bf16x8 a[2];
        #pragma unroll
        for (int mt = 0; mt < 2; ++mt)
            a[mt] = *(const bf16x8*)(as_ + arow[mt] * 256 +
                      ((ks2 * 32 + l16 * 8) ^ ((arow[mt] & 7) << 3)));
        #pragma unroll
        for (int nt = 0; nt < 8; ++nt) {
            bf16x8 b = *(const bf16x8*)(wb + (nt * 8 + ks2) * 512 + lane * 8);
            #pragma unroll
            for (int mt = 0; mt < 2; ++mt)
                acc[mt][nt] = __builtin_amdgcn_mfma_f32_16x16x32_bf16(
                    a[mt], b, acc[mt][nt], 0, 0, 0);
        }
    }

    #pragma unroll
    for (int nt = 0; nt < 8; ++nt) {
        int col = ng * 128 + nt * 16 + l15;
        float bias = pb[col];
        #pragma unroll
        for (int mt = 0; mt < 2; ++mt) {
            int r0 = (mg * 2 + mt) * 16 + l16 * 4;
            #pragma unroll
            for (int j = 0; j < 4; ++j)
                io[((size_t)blockIdx.x * 64 + r0 + j) * DIM + col] =
                    acc[mt][nt][j] + bias;
        }
    }
}

extern "C" void kernel_launch(void* const* d_in, const int* in_sizes, int n_in,
                              void* d_out, int out_size, void* d_ws, size_t ws_size,
                              hipStream_t stream) {
    const float* x    = (const float*)d_in[0];
    const float* mask = (const float*)d_in[1];
    const float* qkvw = (const float*)d_in[2];
    const float* qkvb = (const float*)d_in[3];
    const float* pw   = (const float*)d_in[4];
    const float* pb   = (const float*)d_in[5];
    const float* bt   = (const float*)d_in[6];
    const int*   ri   = (const int*)d_in[7];
    float* out = (float*)d_out;

    unsigned short* wqf = (unsigned short*)d_ws;
    unsigned short* wpf = wqf + 196608;
    float* bmall = (float*)((char*)d_ws + 524288);

    const int nwin = in_sizes[0] / (NTOK * DIM);   // 4096
    const int total = 262144 + 64 * HEADS * 2401;  // 1491456

    k0_prep<<<(total + 255) / 256, 256, 0, stream>>>(qkvw, pw, mask, bt, ri,
                                                     wqf, wpf, bmall, total);
    k1_attn<<<nwin, 256, 0, stream>>>(x, qkvb, wqf, bmall, out);
    k2_proj<<<(nwin * NTOK) / 64, 256, 0, stream>>>(wpf, pb, out);
}

// Round 4
// 419.433 us; speedup vs baseline: 27.4400x; 1.1641x over previous
//
#include <hip/hip_runtime.h>
#include <hip/hip_bf16.h>

#define NTOK 49
#define DIM 256
#define HEADS 8
#define HD 32
#define SCALE 0.17677669529663687f

typedef float f32x4 __attribute__((ext_vector_type(4)));
typedef short bf16x8 __attribute__((ext_vector_type(8)));

__device__ __forceinline__ unsigned short f2bf(float f) {
    union { __hip_bfloat16 h; unsigned short u; } c;
    c.h = __float2bfloat16(f);
    return c.u;
}

// 16-lane-row rotate (DPP row_ror:N); used for softmax reductions over l15.
template<int CTRL>
__device__ __forceinline__ float dpp_rot(float x) {
    int i = __builtin_bit_cast(int, x);
    int r = __builtin_amdgcn_update_dpp(i, i, CTRL, 0xF, 0xF, true);
    return __builtin_bit_cast(float, r);
}

// ---------------------------------------------------------------------------
// K0: one-time prep into d_ws:
//   wqf [196608] bf16 : qkv_w in MFMA B-fragment order
//   wpf [65536]  bf16 : proj_w in MFMA B-fragment order
//   bmall [64][8][49*49] f32 : mask[w,i,j] + bias_table[rel_idx[i,j], h]
// ---------------------------------------------------------------------------
__global__ void k0_prep(const float* __restrict__ qkv_w, const float* __restrict__ proj_w,
                        const float* __restrict__ mask, const float* __restrict__ bias_table,
                        const int* __restrict__ rel_idx,
                        unsigned short* __restrict__ wqf, unsigned short* __restrict__ wpf,
                        float* __restrict__ bmall, int total)
{
    int i = blockIdx.x * 256 + threadIdx.x;
    if (i >= total) return;
    if (i < 196608) {
        int j = i & 7, q = i >> 3;
        int lane = q & 63; q >>= 6;
        int ks2 = q & 7;  q >>= 3;
        int tt = q % 3;   q /= 3;
        int ng = q & 1;
        int h  = q >> 1;
        int n96 = (ng * 3 + tt) * 16 + (lane & 15);
        int seg = n96 >> 5, ch = n96 & 31;
        int srow = seg * 256 + h * HD + ch;
        int scol = ks2 * 32 + (lane >> 4) * 8 + j;
        wqf[i] = f2bf(qkv_w[srow * 256 + scol]);
    } else if (i < 262144) {
        int u = i - 196608;
        int j = u & 7, q = u >> 3;
        int lane = q & 63; q >>= 6;
        int ks2 = q & 7;  q >>= 3;
        int nt = q & 7;
        int ng = q >> 3;
        int n = ng * 128 + nt * 16 + (lane & 15);
        int scol = ks2 * 32 + (lane >> 4) * 8 + j;
        wpf[u] = f2bf(proj_w[n * 256 + scol]);
    } else {
        int u = i - 262144;                 // [0, 64*8*2401)
        int w = u / 19208, rem = u % 19208; // 19208 = 8*2401
        int h = rem / 2401, ij = rem % 2401;
        bmall[u] = mask[w * 2401 + ij] + bias_table[rel_idx[ij] * HEADS + h];
    }
}

// ---------------------------------------------------------------------------
// K1: fused qkv + attention per window. 4096 blocks x 256 threads (4 waves).
// LDS pool 38016 B -> 4 blocks/CU. ps aliases qs/ksh (dead after S-MFMA).
//   xs  [49][256] bf16 swizzled       offset 0      (12544 sh)
//   qs  [52][40]  bf16                offset 12544  ( 2080 sh)
//   ksh [52][40]  bf16                offset 14624  ( 2080 sh)
//   vts [32][72]  bf16 (v^T)          offset 16704  ( 2304 sh)
//   ps  [52][64]  bf16 swizzled       offset 12544  (aliases qs+ksh)
// Rows >= 49 are junk-but-finite everywhere; masked/discarded downstream.
// ---------------------------------------------------------------------------
template<bool BF16AO>
__global__ __launch_bounds__(256, 4) void k1_attn(
    const float* __restrict__ x,             // [4096,49,256] f32
    const float* __restrict__ qkv_b,         // [768] f32
    const unsigned short* __restrict__ wqf,  // fragment-ordered qkv_w bf16
    const float* __restrict__ bmall,         // [64,8,2401] f32
    float* __restrict__ ao32,                // [4096,49,256] f32 (if !BF16AO)
    unsigned short* __restrict__ ao16)       // [4096,49,256] bf16 (if BF16AO)
{
    __shared__ unsigned short pool[19008];
    unsigned short* const xs  = pool;
    unsigned short* const qs  = pool + 12544;
    unsigned short* const ksh = pool + 14624;
    unsigned short* const vts = pool + 16704;
    unsigned short* const ps  = pool + 12544;

    const int t = threadIdx.x;
    const int bw = blockIdx.x;
    const int lane = t & 63;
    const int wv = t >> 6;
    const int l15 = lane & 15, l16 = lane >> 4;
    const int mg = wv >> 1, ng = wv & 1;

    // ---- stage x rows 0..48 -> bf16 LDS (XOR swizzle on 16B chunks)
    const float* xw = x + (size_t)bw * NTOK * DIM;
    for (int cidx = t; cidx < 49 * 32; cidx += 256) {
        int row = cidx >> 5, c8 = cidx & 31;
        float4 a = *(const float4*)(xw + row * DIM + c8 * 8);
        float4 b = *(const float4*)(xw + row * DIM + c8 * 8 + 4);
        bf16x8 v;
        v[0] = (short)f2bf(a.x); v[1] = (short)f2bf(a.y);
        v[2] = (short)f2bf(a.z); v[3] = (short)f2bf(a.w);
        v[4] = (short)f2bf(b.x); v[5] = (short)f2bf(b.y);
        v[6] = (short)f2bf(b.z); v[7] = (short)f2bf(b.w);
        *(bf16x8*)(xs + row * 256 + ((c8 * 8) ^ ((row & 7) << 3))) = v;
    }

    const float* bmh_base = bmall + (size_t)(bw & 63) * 8 * 2401;
    const int rb = wv * 16 + l16 * 4;            // softmax row base
    int arow[2];
    #pragma unroll
    for (int mt = 0; mt < 2; ++mt) {
        int r = (mg * 2 + mt) * 16 + l15;
        arow[mt] = r > 48 ? 48 : r;              // xs has 49 rows
    }
    int rowq = wv * 16 + l15; if (rowq > 51) rowq = 51;
    int prow = wv * 16 + l15; if (prow > 48) prow = 48;
    int brow[4];
    #pragma unroll
    for (int nt = 0; nt < 4; ++nt) {
        int r = nt * 16 + l15;
        brow[nt] = r > 51 ? 51 : r;              // ksh has 52 rows
    }

    for (int h = 0; h < HEADS; ++h) {
        // ---- prefetches issued before barrier A (overlap prior PV / skew)
        const float* bmh = bmh_base + h * 2401;
        float bm[4][4];
        #pragma unroll
        for (int j = 0; j < 4; ++j) {
            int r = rb + j;
            #pragma unroll
            for (int nt = 0; nt < 4; ++nt) {
                int c = nt * 16 + l15;
                bm[j][nt] = (r < NTOK && c < NTOK) ? bmh[r * NTOK + c] : 0.f;
            }
        }
        const unsigned short* wb = wqf + ((size_t)(h * 2 + ng) * 24) * 512;
        bf16x8 b0[3];
        #pragma unroll
        for (int tt = 0; tt < 3; ++tt)
            b0[tt] = *(const bf16x8*)(wb + (tt * 8) * 512 + lane * 8);

        __syncthreads();   // barrier A: prev head's PV reads of ps/vts done

        // ---------- qkv GEMM: wave (mg,ng): 2 M-tiles x 3 N-tiles ----------
        f32x4 acc[2][3];
        #pragma unroll
        for (int mt = 0; mt < 2; ++mt)
            #pragma unroll
            for (int tt = 0; tt < 3; ++tt) acc[mt][tt] = (f32x4){0.f,0.f,0.f,0.f};

        #pragma unroll
        for (int ks2 = 0; ks2 < 8; ++ks2) {
            bf16x8 a[2], b[3];
            #pragma unroll
            for (int mt = 0; mt < 2; ++mt)
                a[mt] = *(const bf16x8*)(xs + arow[mt] * 256 +
                          ((ks2 * 32 + l16 * 8) ^ ((arow[mt] & 7) << 3)));
            #pragma unroll
            for (int tt = 0; tt < 3; ++tt)
                b[tt] = (ks2 == 0) ? b0[tt]
                      : *(const bf16x8*)(wb + (tt * 8 + ks2) * 512 + lane * 8);
            #pragma unroll
            for (int mt = 0; mt < 2; ++mt)
                #pragma unroll
                for (int tt = 0; tt < 3; ++tt)
                    acc[mt][tt] = __builtin_amdgcn_mfma_f32_16x16x32_bf16(
                        a[mt], b[tt], acc[mt][tt], 0, 0, 0);
        }

        // store q (scaled) / k row-major [tok][ch] (rows <52); v^T [ch][tok]
        #pragma unroll
        for (int tt = 0; tt < 3; ++tt) {
            int n96 = (ng * 3 + tt) * 16 + l15;
            int seg = n96 >> 5, ch = n96 & 31;
            float bias = qkv_b[seg * 256 + h * HD + ch];
            #pragma unroll
            for (int mt = 0; mt < 2; ++mt) {
                int r0 = (mg * 2 + mt) * 16 + l16 * 4;
                if (seg == 2) {
                    unsigned int lo = (unsigned)f2bf(acc[mt][tt][0] + bias) |
                                      ((unsigned)f2bf(acc[mt][tt][1] + bias) << 16);
                    unsigned int hi = (unsigned)f2bf(acc[mt][tt][2] + bias) |
                                      ((unsigned)f2bf(acc[mt][tt][3] + bias) << 16);
                    *(uint2*)(vts + ch * 72 + r0) = make_uint2(lo, hi);
                } else if (seg == 0) {
                    #pragma unroll
                    for (int j = 0; j < 4; ++j)
                        if (r0 + j < 52)
                            qs[(r0 + j) * 40 + ch] = f2bf((acc[mt][tt][j] + bias) * SCALE);
                } else {
                    #pragma unroll
                    for (int j = 0; j < 4; ++j)
                        if (r0 + j < 52)
                            ksh[(r0 + j) * 40 + ch] = f2bf(acc[mt][tt][j] + bias);
                }
            }
        }
        __syncthreads();   // barrier B: q/k/vT ready

        // ---------- S = q k^T : wave owns M-tile wv ----------
        bf16x8 aq = *(const bf16x8*)(qs + rowq * 40 + l16 * 8);
        f32x4 s[4];
        #pragma unroll
        for (int nt = 0; nt < 4; ++nt) {
            bf16x8 bk = *(const bf16x8*)(ksh + brow[nt] * 40 + l16 * 8);
            f32x4 z = (f32x4){0.f,0.f,0.f,0.f};
            s[nt] = __builtin_amdgcn_mfma_f32_16x16x32_bf16(aq, bk, z, 0, 0, 0);
        }

        // ---------- in-register softmax; reductions over l15 via DPP -------
        #pragma unroll
        for (int j = 0; j < 4; ++j) {
            float mx = -1e30f;
            #pragma unroll
            for (int nt = 0; nt < 4; ++nt) {
                int c = nt * 16 + l15;
                float v = s[nt][j] + bm[j][nt];
                if (c >= NTOK) v = -1e30f;      // overwrite kills any junk/NaN
                s[nt][j] = v;
                mx = fmaxf(mx, v);
            }
            mx = fmaxf(mx, dpp_rot<0x121>(mx));
            mx = fmaxf(mx, dpp_rot<0x122>(mx));
            mx = fmaxf(mx, dpp_rot<0x124>(mx));
            mx = fmaxf(mx, dpp_rot<0x128>(mx));
            float sum = 0.f;
            #pragma unroll
            for (int nt = 0; nt < 4; ++nt) {
                float e = __expf(s[nt][j] - mx);
                s[nt][j] = e;
                sum += e;
            }
            sum += dpp_rot<0x121>(sum);
            sum += dpp_rot<0x122>(sum);
            sum += dpp_rot<0x124>(sum);
            sum += dpp_rot<0x128>(sum);
            float inv = 1.f / sum;
            #pragma unroll
            for (int nt = 0; nt < 4; ++nt) s[nt][j] *= inv;
        }
        __syncthreads();   // barrier B2: all waves' S reads of qs/ksh done

        // ---------- P -> ps (aliases qs/ksh) ----------
        #pragma unroll
        for (int j = 0; j < 4; ++j) {
            int r = rb + j;
            if (r < 52) {
                #pragma unroll
                for (int nt = 0; nt < 4; ++nt) {
                    int c = nt * 16 + l15;
                    ps[r * 64 + (c ^ ((r & 7) << 3))] = f2bf(s[nt][j]);
                }
            }
        }
        __syncthreads();   // barrier C: P ready

        // ---------- out = P @ v : wave owns M-tile wv, 2 N-tiles ----------
        f32x4 o[2] = {(f32x4){0.f,0.f,0.f,0.f}, (f32x4){0.f,0.f,0.f,0.f}};
        #pragma unroll
        for (int kt = 0; kt < 2; ++kt) {
            bf16x8 ap = *(const bf16x8*)(ps + prow * 64 +
                          ((kt * 32 + l16 * 8) ^ ((prow & 7) << 3)));
            #pragma unroll
            for (int nt = 0; nt < 2; ++nt) {
                bf16x8 bv = *(const bf16x8*)(vts + (nt * 16 + l15) * 72 +
                                             kt * 32 + l16 * 8);
                o[nt] = __builtin_amdgcn_mfma_f32_16x16x32_bf16(ap, bv, o[nt], 0, 0, 0);
            }
        }
        int r0 = wv * 16 + l16 * 4;
        #pragma unroll
        for (int nt = 0; nt < 2; ++nt) {
            int chh = nt * 16 + l15;
            #pragma unroll
            for (int j = 0; j < 4; ++j) {
                int tok = r0 + j;
                if (tok < NTOK) {
                    size_t idx = ((size_t)bw * NTOK + tok) * DIM + h * HD + chh;
                    if (BF16AO) ao16[idx] = f2bf(o[nt][j]);
                    else        ao32[idx] = o[nt][j];
                }
            }
        }
    }
}

// ---------------------------------------------------------------------------
// K2: output projection. BF16AO: reads bf16 ao from ws, writes f32 d_out.
// Fallback: in place on d_out (stage 64 rows to LDS first). MFMA bf16.
// ---------------------------------------------------------------------------
template<bool BF16AO>
__global__ __launch_bounds__(256, 4) void k2_proj(
    const unsigned short* __restrict__ wpf,  // fragment-ordered proj_w bf16
    const float* __restrict__ pb,            // [256]
    const unsigned short* __restrict__ aob,  // bf16 ao (if BF16AO)
    float* __restrict__ io)                  // [200704,256] f32 out
{
    __shared__ unsigned short as_[64 * 256];

    const int t = threadIdx.x;
    const int lane = t & 63;
    const int wv = t >> 6;
    const int l15 = lane & 15, l16 = lane >> 4;
    const int mg = wv >> 1, ng = wv & 1;

    if (BF16AO) {
        const unsigned short* src = aob + (size_t)blockIdx.x * 64 * DIM;
        for (int cidx = t; cidx < 2048; cidx += 256) {
            int row = cidx >> 5, c8 = cidx & 31;
            bf16x8 v = *(const bf16x8*)(src + row * DIM + c8 * 8);
            *(bf16x8*)(as_ + row * 256 + ((c8 * 8) ^ ((row & 7) << 3))) = v;
        }
    } else {
        const float* src = io + (size_t)blockIdx.x * 64 * DIM;
        for (int cidx = t; cidx < 2048; cidx += 256) {
            int row = cidx >> 5, c8 = cidx & 31;
            float4 a = *(const float4*)(src + row * DIM + c8 * 8);
            float4 b = *(const float4*)(src + row * DIM + c8 * 8 + 4);
            bf16x8 v;
            v[0] = (short)f2bf(a.x); v[1] = (short)f2bf(a.y);
            v[2] = (short)f2bf(a.z); v[3] = (short)f2bf(a.w);
            v[4] = (short)f2bf(b.x); v[5] = (short)f2bf(b.y);
            v[6] = (short)f2bf(b.z); v[7] = (short)f2bf(b.w);
            *(bf16x8*)(as_ + row * 256 + ((c8 * 8) ^ ((row & 7) << 3))) = v;
        }
    }
    __syncthreads();

    f32x4 acc[2][8];
    #pragma unroll
    for (int mt = 0; mt < 2; ++mt)
        #pragma unroll
        for (int nt = 0; nt < 8; ++nt) acc[mt][nt] = (f32x4){0.f,0.f,0.f,0.f};

    int arow[2];
    #pragma unroll
    for (int mt = 0; mt < 2; ++mt) arow[mt] = (mg * 2 + mt) * 16 + l15;

    const unsigned short* wb = wpf + (size_t)ng * 8 * 8 * 512;

    #pragma unroll
    for (int ks2 = 0; ks2 < 8; ++ks2) {
        bf16x8 a[2];
        #pragma unroll
        for (int mt = 0; mt < 2; ++mt)
            a[mt] = *(const bf16x8*)(as_ + arow[mt] * 256 +
                      ((ks2 * 32 + l16 * 8) ^ ((arow[mt] & 7) << 3)));
        #pragma unroll
        for (int nt = 0; nt < 8; ++nt) {
            bf16x8 b = *(const bf16x8*)(wb + (nt * 8 + ks2) * 512 + lane * 8);
            #pragma unroll
            for (int mt = 0; mt < 2; ++mt)
                acc[mt][nt] = __builtin_amdgcn_mfma_f32_16x16x32_bf16(
                    a[mt], b, acc[mt][nt], 0, 0, 0);
        }
    }

    #pragma unroll
    for (int nt = 0; nt < 8; ++nt) {
        int col = ng * 128 + nt * 16 + l15;
        float bias = pb[col];
        #pragma unroll
        for (int mt = 0; mt < 2; ++mt) {
            int r0 = (mg * 2 + mt) * 16 + l16 * 4;
            #pragma unroll
            for (int j = 0; j < 4; ++j)
                io[((size_t)blockIdx.x * 64 + r0 + j) * DIM + col] =
                    acc[mt][nt][j] + bias;
        }
    }
}

extern "C" void kernel_launch(void* const* d_in, const int* in_sizes, int n_in,
                              void* d_out, int out_size, void* d_ws, size_t ws_size,
                              hipStream_t stream) {
    const float* x    = (const float*)d_in[0];
    const float* mask = (const float*)d_in[1];
    const float* qkvw = (const float*)d_in[2];
    const float* qkvb = (const float*)d_in[3];
    const float* pw   = (const float*)d_in[4];
    const float* pb   = (const float*)d_in[5];
    const float* bt   = (const float*)d_in[6];
    const int*   ri   = (const int*)d_in[7];
    float* out = (float*)d_out;

    unsigned short* wqf = (unsigned short*)d_ws;
    unsigned short* wpf = wqf + 196608;
    float* bmall = (float*)((char*)d_ws + 524288);
    // bmall: 64*8*2401 f32 = 4,917,248 B -> ends at 5,441,536
    unsigned short* aob = (unsigned short*)((char*)d_ws + 5441536);

    const int nwin = in_sizes[0] / (NTOK * DIM);   // 4096
    const int total = 262144 + 64 * HEADS * 2401;  // 1491456
    const size_t need = 5441536ULL + (size_t)nwin * NTOK * DIM * 2;
    const bool b16 = ws_size >= need;

    k0_prep<<<(total + 255) / 256, 256, 0, stream>>>(qkvw, pw, mask, bt, ri,
                                                     wqf, wpf, bmall, total);
    if (b16) {
        k1_attn<true><<<nwin, 256, 0, stream>>>(x, qkvb, wqf, bmall, nullptr, aob);
        k2_proj<true><<<(nwin * NTOK) / 64, 256, 0, stream>>>(wpf, pb, aob, out);
    } else {
        k1_attn<false><<<nwin, 256, 0, stream>>>(x, qkvb, wqf, bmall, out, nullptr);
        k2_proj<false><<<(nwin * NTOK) / 64, 256, 0, stream>>>(wpf, pb, nullptr, out);
    }
}

// Round 5
// 336.078 us; speedup vs baseline: 34.2457x; 1.2480x over previous
//
#include <hip/hip_runtime.h>
#include <hip/hip_bf16.h>

#define NTOK 49
#define DIM 256
#define HEADS 8
#define HD 32
#define SCALE 0.17677669529663687f

typedef float f32x4 __attribute__((ext_vector_type(4)));
typedef short bf16x8 __attribute__((ext_vector_type(8)));

__device__ __forceinline__ unsigned short f2bf(float f) {
    union { __hip_bfloat16 h; unsigned short u; } c;
    c.h = __float2bfloat16(f);
    return c.u;
}
__device__ __forceinline__ float bf2f(unsigned short u) {
    return __builtin_bit_cast(float, (unsigned)u << 16);
}

// 16-lane-row rotate (DPP row_ror:N); softmax reductions over l15.
template<int CTRL>
__device__ __forceinline__ float dpp_rot(float x) {
    int i = __builtin_bit_cast(int, x);
    int r = __builtin_amdgcn_update_dpp(i, i, CTRL, 0xF, 0xF, true);
    return __builtin_bit_cast(float, r);
}

// ---------------------------------------------------------------------------
// K0: one-time prep into d_ws:
//   wqf [196608] bf16 : qkv_w in MFMA B-fragment order
//       idx = ((h*6 + tt)*8 + ks2)*512 + lane*8 + j
//       -> qkv_w[(seg*256 + h*32 + ch)*256 + ks2*32 + (lane>>4)*8 + j],
//          n96 = tt*16 + (lane&15), seg = n96>>5, ch = n96&31
//   wpf [65536] bf16  : proj_w in MFMA B-fragment order
//       idx = (bt*8 + ks2)*512 + lane*8 + j
//       -> proj_w[((bt>>3)*128 + (bt&7)*16 + (lane&15))*256 + ks2*32 + (lane>>4)*8 + j]
//   bmf [2097152] bf16 : mask+bias in softmax D-fragment order
//       idx = (wslot*128 + h*16 + mt*4 + jj)*256 + lane*4 + nt
//       -> value at S row r = mt*16+(lane>>4)*4+jj, col c = nt*16+(lane&15)
// ---------------------------------------------------------------------------
__global__ void k0_prep(const float* __restrict__ qkv_w, const float* __restrict__ proj_w,
                        const float* __restrict__ mask, const float* __restrict__ bias_table,
                        const int* __restrict__ rel_idx,
                        unsigned short* __restrict__ wqf, unsigned short* __restrict__ wpf,
                        unsigned short* __restrict__ bmf, int total)
{
    int i = blockIdx.x * 256 + threadIdx.x;
    if (i >= total) return;
    if (i < 196608) {
        int j = i & 7, q = i >> 3;
        int lane = q & 63; q >>= 6;
        int ks2 = q & 7;  q >>= 3;
        int tt = q % 6;   q /= 6;
        int h  = q;
        int n96 = tt * 16 + (lane & 15);
        int seg = n96 >> 5, ch = n96 & 31;
        wqf[i] = f2bf(qkv_w[(seg * 256 + h * HD + ch) * 256 + ks2 * 32 + (lane >> 4) * 8 + j]);
    } else if (i < 262144) {
        int u = i - 196608;
        int j = u & 7, q = u >> 3;
        int lane = q & 63; q >>= 6;
        int ks2 = q & 7;  q >>= 3;
        int bt = q;                       // 0..15
        int n = (bt >> 3) * 128 + (bt & 7) * 16 + (lane & 15);
        wpf[u] = f2bf(proj_w[n * 256 + ks2 * 32 + (lane >> 4) * 8 + j]);
    } else {
        int u = i - 262144;               // [0, 2097152)
        int nt = u & 3;
        int lane = (u >> 2) & 63;
        int g = u >> 8;                   // wslot*128 + h*16 + mt*4 + jj
        int jj = g & 3, mt = (g >> 2) & 3, h = (g >> 4) & 7, ws = g >> 7;
        int r = mt * 16 + (lane >> 4) * 4 + jj;
        int c = nt * 16 + (lane & 15);
        float v = 0.f;
        if (r < NTOK && c < NTOK)
            v = mask[ws * 2401 + r * NTOK + c] + bias_table[rel_idx[r * NTOK + c] * HEADS + h];
        bmf[u] = f2bf(v);
    }
}

// ---------------------------------------------------------------------------
// K1: fully fused qkv + attention + proj. 4096 blocks x 256 threads (4 waves).
// Each wave owns heads {wv, wv+4} end-to-end with wave-PRIVATE LDS buffers:
// no barriers inside the head pipeline. 3 barriers total per block.
// LDS pool 76800 B (static) -> 2 blocks/CU:
//   xs  [49][256] bf16 swizzled     sh [0,12544)   (x; later reused for ao)
//   per wave wv at base W = 12544 + wv*6464:
//     qw  [52][40] bf16             W+0    (2080)
//     kw  [52][40] bf16             W+2080 (2080)
//     vtw [32][72] bf16 (v^T)       W+4160 (2304)
//     pw_ [52][64] bf16 swizzled    W+0    (3328, aliases qw/kw; safe: S-reads
//                                    complete before P-writes issue, in-wave)
// ---------------------------------------------------------------------------
__global__ __launch_bounds__(256, 2) void k1_fused(
    const float* __restrict__ x,             // [4096,49,256] f32
    const float* __restrict__ qkv_b,         // [768] f32
    const float* __restrict__ pb,            // [256] f32
    const unsigned short* __restrict__ wqf,  // fragment-ordered qkv_w bf16
    const unsigned short* __restrict__ wpf,  // fragment-ordered proj_w bf16
    const unsigned short* __restrict__ bmf,  // fragment-ordered mask+bias bf16
    float* __restrict__ out)                 // [4096,49,256] f32 final
{
    __shared__ unsigned short pool[38400];
    unsigned short* const xs = pool;

    const int t = threadIdx.x, bw = blockIdx.x;
    const int lane = t & 63, wv = t >> 6;
    const int l15 = lane & 15, l16 = lane >> 4;
    unsigned short* const qw  = pool + 12544 + wv * 6464;
    unsigned short* const kw  = qw + 2080;
    unsigned short* const vtw = qw + 4160;
    unsigned short* const pw_ = qw;

    // ---- stage x rows 0..48 -> bf16 LDS (XOR swizzle on 16B chunks)
    const float* xw = x + (size_t)bw * NTOK * DIM;
    for (int cidx = t; cidx < NTOK * 32; cidx += 256) {
        int row = cidx >> 5, c8 = cidx & 31;
        float4 a = *(const float4*)(xw + row * DIM + c8 * 8);
        float4 b = *(const float4*)(xw + row * DIM + c8 * 8 + 4);
        bf16x8 v;
        v[0] = (short)f2bf(a.x); v[1] = (short)f2bf(a.y);
        v[2] = (short)f2bf(a.z); v[3] = (short)f2bf(a.w);
        v[4] = (short)f2bf(b.x); v[5] = (short)f2bf(b.y);
        v[6] = (short)f2bf(b.z); v[7] = (short)f2bf(b.w);
        *(bf16x8*)(xs + row * 256 + ((c8 * 8) ^ ((row & 7) << 3))) = v;
    }
    __syncthreads();   // barrier 1: xs ready

    int arow[4], rq[4];
    #pragma unroll
    for (int mt = 0; mt < 4; ++mt) {
        int r = mt * 16 + l15;
        arow[mt] = r > 48 ? 48 : r;     // xs / pw_ reads (49 real rows)
        rq[mt]   = r > 51 ? 51 : r;     // qw / kw reads (52 rows)
    }
    const int wimg = (bw & 63) << 7;

    f32x4 oall[2][4][2];

    #pragma unroll
    for (int hh = 0; hh < 2; ++hh) {
        const int h = wv + 4 * hh;
        const unsigned short* wb = wqf + (size_t)h * 24576;
        ushort4 bmu[4][4];

        // ---------- qkv GEMM: 4 M-tiles x 6 N-tiles, two register passes ----
        #pragma unroll
        for (int p = 0; p < 2; ++p) {
            f32x4 acc[4][3];
            #pragma unroll
            for (int mt = 0; mt < 4; ++mt)
                #pragma unroll
                for (int tt = 0; tt < 3; ++tt) acc[mt][tt] = (f32x4){0.f,0.f,0.f,0.f};

            #pragma unroll
            for (int ks2 = 0; ks2 < 8; ++ks2) {
                bf16x8 a[4], b[3];
                #pragma unroll
                for (int mt = 0; mt < 4; ++mt)
                    a[mt] = *(const bf16x8*)(xs + arow[mt] * 256 +
                              ((ks2 * 32 + l16 * 8) ^ ((arow[mt] & 7) << 3)));
                #pragma unroll
                for (int tt = 0; tt < 3; ++tt)
                    b[tt] = *(const bf16x8*)(wb + ((p * 3 + tt) * 8 + ks2) * 512 + lane * 8);
                #pragma unroll
                for (int mt = 0; mt < 4; ++mt)
                    #pragma unroll
                    for (int tt = 0; tt < 3; ++tt)
                        acc[mt][tt] = __builtin_amdgcn_mfma_f32_16x16x32_bf16(
                            a[mt], b[tt], acc[mt][tt], 0, 0, 0);
            }

            if (p == 0) {   // prefetch softmax bias+mask frags (hide under pass 1)
                #pragma unroll
                for (int mt = 0; mt < 4; ++mt)
                    #pragma unroll
                    for (int jj = 0; jj < 4; ++jj)
                        bmu[mt][jj] = *(const ushort4*)(bmf +
                            (((size_t)(wimg + h * 16 + mt * 4 + jj)) << 8) + (lane << 2));
            }

            // epilogue: q (scaled) / k row-major; v transposed
            #pragma unroll
            for (int tt = 0; tt < 3; ++tt) {
                int n96 = (p * 3 + tt) * 16 + l15;
                int seg = n96 >> 5, ch = n96 & 31;
                float bias = qkv_b[seg * 256 + h * HD + ch];
                #pragma unroll
                for (int mt = 0; mt < 4; ++mt) {
                    int r0 = mt * 16 + l16 * 4;
                    if (seg == 2) {
                        unsigned int lo = (unsigned)f2bf(acc[mt][tt][0] + bias) |
                                          ((unsigned)f2bf(acc[mt][tt][1] + bias) << 16);
                        unsigned int hi = (unsigned)f2bf(acc[mt][tt][2] + bias) |
                                          ((unsigned)f2bf(acc[mt][tt][3] + bias) << 16);
                        *(uint2*)(vtw + ch * 72 + r0) = make_uint2(lo, hi);
                    } else if (seg == 0) {
                        #pragma unroll
                        for (int j = 0; j < 4; ++j)
                            if (r0 + j < 52)
                                qw[(r0 + j) * 40 + ch] = f2bf((acc[mt][tt][j] + bias) * SCALE);
                    } else {
                        #pragma unroll
                        for (int j = 0; j < 4; ++j)
                            if (r0 + j < 52)
                                kw[(r0 + j) * 40 + ch] = f2bf(acc[mt][tt][j] + bias);
                    }
                }
            }
        }

        // ---------- S = q k^T : 4x4 tiles, K=32 in one MFMA ----------
        bf16x8 aq[4], bk[4];
        #pragma unroll
        for (int mt = 0; mt < 4; ++mt)
            aq[mt] = *(const bf16x8*)(qw + rq[mt] * 40 + l16 * 8);
        #pragma unroll
        for (int nt = 0; nt < 4; ++nt)
            bk[nt] = *(const bf16x8*)(kw + rq[nt] * 40 + l16 * 8);
        f32x4 s[4][4];
        #pragma unroll
        for (int mt = 0; mt < 4; ++mt)
            #pragma unroll
            for (int nt = 0; nt < 4; ++nt) {
                f32x4 z = (f32x4){0.f,0.f,0.f,0.f};
                s[mt][nt] = __builtin_amdgcn_mfma_f32_16x16x32_bf16(aq[mt], bk[nt], z, 0, 0, 0);
            }

        // ---------- in-register softmax (DPP over l15) + P -> pw_ ----------
        #pragma unroll
        for (int mt = 0; mt < 4; ++mt) {
            #pragma unroll
            for (int j = 0; j < 4; ++j) {
                int r = mt * 16 + l16 * 4 + j;
                float bmv[4] = { bf2f(bmu[mt][j].x), bf2f(bmu[mt][j].y),
                                 bf2f(bmu[mt][j].z), bf2f(bmu[mt][j].w) };
                float vv[4];
                float mx = -1e30f;
                #pragma unroll
                for (int nt = 0; nt < 4; ++nt) {
                    int c = nt * 16 + l15;
                    float v = s[mt][nt][j] + bmv[nt];
                    if (c >= NTOK) v = -1e30f;
                    vv[nt] = v;
                    mx = fmaxf(mx, v);
                }
                mx = fmaxf(mx, dpp_rot<0x121>(mx));
                mx = fmaxf(mx, dpp_rot<0x122>(mx));
                mx = fmaxf(mx, dpp_rot<0x124>(mx));
                mx = fmaxf(mx, dpp_rot<0x128>(mx));
                float sum = 0.f;
                #pragma unroll
                for (int nt = 0; nt < 4; ++nt) {
                    float e = __expf(vv[nt] - mx);
                    vv[nt] = e;
                    sum += e;
                }
                sum += dpp_rot<0x121>(sum);
                sum += dpp_rot<0x122>(sum);
                sum += dpp_rot<0x124>(sum);
                sum += dpp_rot<0x128>(sum);
                float inv = 1.f / sum;
                if (r < 52) {
                    #pragma unroll
                    for (int nt = 0; nt < 4; ++nt) {
                        int c = nt * 16 + l15;
                        pw_[r * 64 + (c ^ ((r & 7) << 3))] = f2bf(vv[nt] * inv);
                    }
                }
            }
        }

        // ---------- out_h = P @ v : 4 M-tiles x 2 N-tiles, K=64 ----------
        #pragma unroll
        for (int mt = 0; mt < 4; ++mt)
            #pragma unroll
            for (int nt = 0; nt < 2; ++nt) oall[hh][mt][nt] = (f32x4){0.f,0.f,0.f,0.f};
        #pragma unroll
        for (int kt = 0; kt < 2; ++kt) {
            bf16x8 ap[4];
            #pragma unroll
            for (int mt = 0; mt < 4; ++mt)
                ap[mt] = *(const bf16x8*)(pw_ + arow[mt] * 64 +
                           ((kt * 32 + l16 * 8) ^ ((arow[mt] & 7) << 3)));
            #pragma unroll
            for (int nt = 0; nt < 2; ++nt) {
                bf16x8 bv = *(const bf16x8*)(vtw + (nt * 16 + l15) * 72 + kt * 32 + l16 * 8);
                #pragma unroll
                for (int mt = 0; mt < 4; ++mt)
                    oall[hh][mt][nt] = __builtin_amdgcn_mfma_f32_16x16x32_bf16(
                        ap[mt], bv, oall[hh][mt][nt], 0, 0, 0);
            }
        }
    }

    __syncthreads();   // barrier 2: all waves past their last xs read

    // ---- scatter attention output (both heads) into xs as bf16, swizzled
    #pragma unroll
    for (int hh = 0; hh < 2; ++hh) {
        #pragma unroll
        for (int mt = 0; mt < 4; ++mt) {
            #pragma unroll
            for (int nt = 0; nt < 2; ++nt) {
                #pragma unroll
                for (int j = 0; j < 4; ++j) {
                    int tok = mt * 16 + l16 * 4 + j;
                    if (tok < NTOK) {
                        int ch = (wv + 4 * hh) * HD + nt * 16 + l15;
                        int ad = tok * 256 + ((ch & ~7) ^ ((tok & 7) << 3)) + (ch & 7);
                        xs[ad] = f2bf(oall[hh][mt][nt][j]);
                    }
                }
            }
        }
    }
    __syncthreads();   // barrier 3: ao ready in xs

    // ---- proj: out = ao @ proj_w^T + pb. Wave covers 4 col-tiles (64 cols).
    f32x4 pacc[4][4];
    #pragma unroll
    for (int mt = 0; mt < 4; ++mt)
        #pragma unroll
        for (int u = 0; u < 4; ++u) pacc[mt][u] = (f32x4){0.f,0.f,0.f,0.f};

    int pcol[4];
    float pbv[4];
    #pragma unroll
    for (int u = 0; u < 4; ++u) {
        int bt = wv * 4 + u;
        pcol[u] = (bt >> 3) * 128 + (bt & 7) * 16 + l15;
        pbv[u] = pb[pcol[u]];
    }

    #pragma unroll
    for (int ks2 = 0; ks2 < 8; ++ks2) {
        bf16x8 a[4];
        #pragma unroll
        for (int mt = 0; mt < 4; ++mt)
            a[mt] = *(const bf16x8*)(xs + arow[mt] * 256 +
                      ((ks2 * 32 + l16 * 8) ^ ((arow[mt] & 7) << 3)));
        #pragma unroll
        for (int u = 0; u < 4; ++u) {
            bf16x8 b = *(const bf16x8*)(wpf + (size_t)((wv * 4 + u) * 8 + ks2) * 512 + lane * 8);
            #pragma unroll
            for (int mt = 0; mt < 4; ++mt)
                pacc[mt][u] = __builtin_amdgcn_mfma_f32_16x16x32_bf16(
                    a[mt], b, pacc[mt][u], 0, 0, 0);
        }
    }

    #pragma unroll
    for (int u = 0; u < 4; ++u) {
        #pragma unroll
        for (int mt = 0; mt < 4; ++mt) {
            #pragma unroll
            for (int j = 0; j < 4; ++j) {
                int tok = mt * 16 + l16 * 4 + j;
                if (tok < NTOK)
                    out[((size_t)bw * NTOK + tok) * DIM + pcol[u]] = pacc[mt][u][j] + pbv[u];
            }
        }
    }
}

extern "C" void kernel_launch(void* const* d_in, const int* in_sizes, int n_in,
                              void* d_out, int out_size, void* d_ws, size_t ws_size,
                              hipStream_t stream) {
    const float* x    = (const float*)d_in[0];
    const float* mask = (const float*)d_in[1];
    const float* qkvw = (const float*)d_in[2];
    const float* qkvb = (const float*)d_in[3];
    const float* pw   = (const float*)d_in[4];
    const float* pb   = (const float*)d_in[5];
    const float* bt   = (const float*)d_in[6];
    const int*   ri   = (const int*)d_in[7];
    float* out = (float*)d_out;

    unsigned short* wqf = (unsigned short*)d_ws;
    unsigned short* wpf = wqf + 196608;
    unsigned short* bmf = (unsigned short*)((char*)d_ws + 524288);  // 4 MB

    const int nwin = in_sizes[0] / (NTOK * DIM);     // 4096
    const int total = 262144 + 64 * HEADS * 16 * 256; // 2359296

    k0_prep<<<(total + 255) / 256, 256, 0, stream>>>(qkvw, pw, mask, bt, ri,
                                                     wqf, wpf, bmf, total);
    k1_fused<<<nwin, 256, 0, stream>>>(x, qkvb, pb, wqf, wpf, bmf, out);
}

// Round 6
// 334.115 us; speedup vs baseline: 34.4469x; 1.0059x over previous
//
#include <hip/hip_runtime.h>
#include <hip/hip_bf16.h>

#define NTOK 49
#define DIM 256
#define HEADS 8
#define HD 32
#define SCALE 0.17677669529663687f

typedef float f32x4 __attribute__((ext_vector_type(4)));
typedef short bf16x8 __attribute__((ext_vector_type(8)));

__device__ __forceinline__ unsigned short f2bf(float f) {
    union { __hip_bfloat16 h; unsigned short u; } c;
    c.h = __float2bfloat16(f);
    return c.u;
}
__device__ __forceinline__ float bf2f(unsigned short u) {
    return __builtin_bit_cast(float, (unsigned)u << 16);
}

// 16-lane-row rotate (DPP row_ror:N); softmax reductions over l15.
template<int CTRL>
__device__ __forceinline__ float dpp_rot(float x) {
    int i = __builtin_bit_cast(int, x);
    int r = __builtin_amdgcn_update_dpp(i, i, CTRL, 0xF, 0xF, true);
    return __builtin_bit_cast(float, r);
}

// ---------------------------------------------------------------------------
// K0: one-time prep into d_ws (unchanged from round 5):
//   wqf [196608] bf16 : qkv_w in MFMA A/B-fragment order
//   wpf [65536]  bf16 : proj_w in MFMA B-fragment order
//   bmf [2097152] bf16 : mask+bias in softmax D-fragment order
// ---------------------------------------------------------------------------
__global__ void k0_prep(const float* __restrict__ qkv_w, const float* __restrict__ proj_w,
                        const float* __restrict__ mask, const float* __restrict__ bias_table,
                        const int* __restrict__ rel_idx,
                        unsigned short* __restrict__ wqf, unsigned short* __restrict__ wpf,
                        unsigned short* __restrict__ bmf, int total)
{
    int i = blockIdx.x * 256 + threadIdx.x;
    if (i >= total) return;
    if (i < 196608) {
        int j = i & 7, q = i >> 3;
        int lane = q & 63; q >>= 6;
        int ks2 = q & 7;  q >>= 3;
        int tt = q % 6;   q /= 6;
        int h  = q;
        int n96 = tt * 16 + (lane & 15);
        int seg = n96 >> 5, ch = n96 & 31;
        wqf[i] = f2bf(qkv_w[(seg * 256 + h * HD + ch) * 256 + ks2 * 32 + (lane >> 4) * 8 + j]);
    } else if (i < 262144) {
        int u = i - 196608;
        int j = u & 7, q = u >> 3;
        int lane = q & 63; q >>= 6;
        int ks2 = q & 7;  q >>= 3;
        int bt = q;                       // 0..15
        int n = (bt >> 3) * 128 + (bt & 7) * 16 + (lane & 15);
        wpf[u] = f2bf(proj_w[n * 256 + ks2 * 32 + (lane >> 4) * 8 + j]);
    } else {
        int u = i - 262144;               // [0, 2097152)
        int nt = u & 3;
        int lane = (u >> 2) & 63;
        int g = u >> 8;                   // wslot*128 + h*16 + mt*4 + jj
        int jj = g & 3, mt = (g >> 2) & 3, h = (g >> 4) & 7, ws = g >> 7;
        int r = mt * 16 + (lane >> 4) * 4 + jj;
        int c = nt * 16 + (lane & 15);
        float v = 0.f;
        if (r < NTOK && c < NTOK)
            v = mask[ws * 2401 + r * NTOK + c] + bias_table[rel_idx[r * NTOK + c] * HEADS + h];
        bmf[u] = f2bf(v);
    }
}

// ---------------------------------------------------------------------------
// K1: fully fused qkv + attention + proj. 4096 blocks x 256 threads (4 waves).
// Wave wv owns heads {wv, wv+4}; wave-private LDS; 3 barriers per block.
// amdgpu_waves_per_eu(2,2): LDS (76800 B) caps at 2 blocks/CU anyway, so give
// the allocator the full 256-VGPR budget -> no scratch spill (round-5 spilled
// ~32 f32/thread: +126 MB HBM writes).
// LDS pool:
//   xs  [49][256] bf16 swizzled     sh [0,12544)   (x; reused for ao)
//   per wave wv at base W = 12544 + wv*6464:
//     qw  [52][40] bf16             W+0    (2080)
//     kw  [52][40] bf16             W+2080 (2080)
//     vtw [32][72] bf16 (v^T)       W+4160 (2304)
//     pw_ [52][64] bf16 swizzled    W+0    (aliases qw/kw; q/k frags are read
//                                    into registers before P is written)
// ---------------------------------------------------------------------------
__global__ __launch_bounds__(256)
__attribute__((amdgpu_waves_per_eu(2, 2)))
void k1_fused(
    const float* __restrict__ x,             // [4096,49,256] f32
    const float* __restrict__ qkv_b,         // [768] f32
    const float* __restrict__ pb,            // [256] f32
    const unsigned short* __restrict__ wqf,  // fragment-ordered qkv_w bf16
    const unsigned short* __restrict__ wpf,  // fragment-ordered proj_w bf16
    const unsigned short* __restrict__ bmf,  // fragment-ordered mask+bias bf16
    float* __restrict__ out)                 // [4096,49,256] f32 final
{
    __shared__ unsigned short pool[38400];
    unsigned short* const xs = pool;

    const int t = threadIdx.x, bw = blockIdx.x;
    const int lane = t & 63, wv = t >> 6;
    const int l15 = lane & 15, l16 = lane >> 4;
    unsigned short* const qw  = pool + 12544 + wv * 6464;
    unsigned short* const kw  = qw + 2080;
    unsigned short* const vtw = qw + 4160;
    unsigned short* const pw_ = qw;

    // ---- stage x rows 0..48 -> bf16 LDS (XOR swizzle on 16B chunks)
    const float* xw = x + (size_t)bw * NTOK * DIM;
    for (int cidx = t; cidx < NTOK * 32; cidx += 256) {
        int row = cidx >> 5, c8 = cidx & 31;
        float4 a = *(const float4*)(xw + row * DIM + c8 * 8);
        float4 b = *(const float4*)(xw + row * DIM + c8 * 8 + 4);
        bf16x8 v;
        v[0] = (short)f2bf(a.x); v[1] = (short)f2bf(a.y);
        v[2] = (short)f2bf(a.z); v[3] = (short)f2bf(a.w);
        v[4] = (short)f2bf(b.x); v[5] = (short)f2bf(b.y);
        v[6] = (short)f2bf(b.z); v[7] = (short)f2bf(b.w);
        *(bf16x8*)(xs + row * 256 + ((c8 * 8) ^ ((row & 7) << 3))) = v;
    }
    __syncthreads();   // barrier 1: xs ready

    int arow[4], rq[4];
    #pragma unroll
    for (int mt = 0; mt < 4; ++mt) {
        int r = mt * 16 + l15;
        arow[mt] = r > 48 ? 48 : r;     // xs / pw_ reads (49 real rows)
        rq[mt]   = r > 51 ? 51 : r;     // qw / kw reads (52 rows)
    }
    const int wimg = (bw & 63) << 7;

    unsigned int ob[2][4][2][2];        // packed bf16 PV outputs (2 heads)

    #pragma unroll
    for (int hh = 0; hh < 2; ++hh) {
        const int h = wv + 4 * hh;
        const unsigned short* wb = wqf + (size_t)h * 24576;
        ushort4 bmu[4][4];

        // ---------- qkv GEMM: 4 M-tiles x 6 N-tiles, two register passes ----
        #pragma unroll
        for (int p = 0; p < 2; ++p) {
            f32x4 acc[4][3];
            #pragma unroll
            for (int mt = 0; mt < 4; ++mt)
                #pragma unroll
                for (int tt = 0; tt < 3; ++tt) acc[mt][tt] = (f32x4){0.f,0.f,0.f,0.f};

            __builtin_amdgcn_s_setprio(1);
            #pragma unroll
            for (int ks2 = 0; ks2 < 8; ++ks2) {
                bf16x8 a[4], b[3];
                #pragma unroll
                for (int mt = 0; mt < 4; ++mt)
                    a[mt] = *(const bf16x8*)(xs + arow[mt] * 256 +
                              ((ks2 * 32 + l16 * 8) ^ ((arow[mt] & 7) << 3)));
                #pragma unroll
                for (int tt = 0; tt < 3; ++tt)
                    b[tt] = *(const bf16x8*)(wb + ((p * 3 + tt) * 8 + ks2) * 512 + lane * 8);
                #pragma unroll
                for (int mt = 0; mt < 4; ++mt)
                    #pragma unroll
                    for (int tt = 0; tt < 3; ++tt)
                        acc[mt][tt] = __builtin_amdgcn_mfma_f32_16x16x32_bf16(
                            a[mt], b[tt], acc[mt][tt], 0, 0, 0);
            }
            __builtin_amdgcn_s_setprio(0);

            if (p == 0) {   // prefetch softmax bias+mask frags (hide under pass 1)
                #pragma unroll
                for (int mt = 0; mt < 4; ++mt)
                    #pragma unroll
                    for (int jj = 0; jj < 4; ++jj)
                        bmu[mt][jj] = *(const ushort4*)(bmf +
                            (((size_t)(wimg + h * 16 + mt * 4 + jj)) << 8) + (lane << 2));
            }

            // epilogue: q (scaled) / k row-major; v transposed
            #pragma unroll
            for (int tt = 0; tt < 3; ++tt) {
                int n96 = (p * 3 + tt) * 16 + l15;
                int seg = n96 >> 5, ch = n96 & 31;
                float bias = qkv_b[seg * 256 + h * HD + ch];
                #pragma unroll
                for (int mt = 0; mt < 4; ++mt) {
                    int r0 = mt * 16 + l16 * 4;
                    if (seg == 2) {
                        unsigned int lo = (unsigned)f2bf(acc[mt][tt][0] + bias) |
                                          ((unsigned)f2bf(acc[mt][tt][1] + bias) << 16);
                        unsigned int hi = (unsigned)f2bf(acc[mt][tt][2] + bias) |
                                          ((unsigned)f2bf(acc[mt][tt][3] + bias) << 16);
                        *(uint2*)(vtw + ch * 72 + r0) = make_uint2(lo, hi);
                    } else if (seg == 0) {
                        #pragma unroll
                        for (int j = 0; j < 4; ++j)
                            if (r0 + j < 52)
                                qw[(r0 + j) * 40 + ch] = f2bf((acc[mt][tt][j] + bias) * SCALE);
                    } else {
                        #pragma unroll
                        for (int j = 0; j < 4; ++j)
                            if (r0 + j < 52)
                                kw[(r0 + j) * 40 + ch] = f2bf(acc[mt][tt][j] + bias);
                    }
                }
            }
        }

        // ---------- read ALL q/k fragments into registers (qw/kw then dead) -
        bf16x8 aq[4], bk[4];
        #pragma unroll
        for (int mt = 0; mt < 4; ++mt)
            aq[mt] = *(const bf16x8*)(qw + rq[mt] * 40 + l16 * 8);
        #pragma unroll
        for (int nt = 0; nt < 4; ++nt)
            bk[nt] = *(const bf16x8*)(kw + rq[nt] * 40 + l16 * 8);

        // ---------- S + softmax + P-store, split in two mt-halves ----------
        #pragma unroll
        for (int half = 0; half < 2; ++half) {
            f32x4 s[2][4];
            __builtin_amdgcn_s_setprio(1);
            #pragma unroll
            for (int m2 = 0; m2 < 2; ++m2)
                #pragma unroll
                for (int nt = 0; nt < 4; ++nt) {
                    f32x4 z = (f32x4){0.f,0.f,0.f,0.f};
                    s[m2][nt] = __builtin_amdgcn_mfma_f32_16x16x32_bf16(
                        aq[half * 2 + m2], bk[nt], z, 0, 0, 0);
                }
            __builtin_amdgcn_s_setprio(0);

            #pragma unroll
            for (int m2 = 0; m2 < 2; ++m2) {
                const int mt = half * 2 + m2;
                #pragma unroll
                for (int j = 0; j < 4; ++j) {
                    int r = mt * 16 + l16 * 4 + j;
                    float bmv[4] = { bf2f(bmu[mt][j].x), bf2f(bmu[mt][j].y),
                                     bf2f(bmu[mt][j].z), bf2f(bmu[mt][j].w) };
                    float vv[4];
                    float mx = -1e30f;
                    #pragma unroll
                    for (int nt = 0; nt < 4; ++nt) {
                        int c = nt * 16 + l15;
                        float v = s[m2][nt][j] + bmv[nt];
                        if (c >= NTOK) v = -1e30f;
                        vv[nt] = v;
                        mx = fmaxf(mx, v);
                    }
                    mx = fmaxf(mx, dpp_rot<0x121>(mx));
                    mx = fmaxf(mx, dpp_rot<0x122>(mx));
                    mx = fmaxf(mx, dpp_rot<0x124>(mx));
                    mx = fmaxf(mx, dpp_rot<0x128>(mx));
                    float sum = 0.f;
                    #pragma unroll
                    for (int nt = 0; nt < 4; ++nt) {
                        float e = __expf(vv[nt] - mx);
                        vv[nt] = e;
                        sum += e;
                    }
                    sum += dpp_rot<0x121>(sum);
                    sum += dpp_rot<0x122>(sum);
                    sum += dpp_rot<0x124>(sum);
                    sum += dpp_rot<0x128>(sum);
                    float inv = 1.f / sum;
                    if (r < 52) {
                        #pragma unroll
                        for (int nt = 0; nt < 4; ++nt) {
                            int c = nt * 16 + l15;
                            pw_[r * 64 + (c ^ ((r & 7) << 3))] = f2bf(vv[nt] * inv);
                        }
                    }
                }
            }
        }

        // ---------- out_h = P @ v : 4 M-tiles x 2 N-tiles, K=64 ----------
        f32x4 o[4][2];
        #pragma unroll
        for (int mt = 0; mt < 4; ++mt)
            #pragma unroll
            for (int nt = 0; nt < 2; ++nt) o[mt][nt] = (f32x4){0.f,0.f,0.f,0.f};
        __builtin_amdgcn_s_setprio(1);
        #pragma unroll
        for (int kt = 0; kt < 2; ++kt) {
            bf16x8 ap[4];
            #pragma unroll
            for (int mt = 0; mt < 4; ++mt)
                ap[mt] = *(const bf16x8*)(pw_ + arow[mt] * 64 +
                           ((kt * 32 + l16 * 8) ^ ((arow[mt] & 7) << 3)));
            #pragma unroll
            for (int nt = 0; nt < 2; ++nt) {
                bf16x8 bv = *(const bf16x8*)(vtw + (nt * 16 + l15) * 72 + kt * 32 + l16 * 8);
                #pragma unroll
                for (int mt = 0; mt < 4; ++mt)
                    o[mt][nt] = __builtin_amdgcn_mfma_f32_16x16x32_bf16(
                        ap[mt], bv, o[mt][nt], 0, 0, 0);
            }
        }
        __builtin_amdgcn_s_setprio(0);

        // pack to bf16 immediately (identical numerics to the later scatter)
        #pragma unroll
        for (int mt = 0; mt < 4; ++mt)
            #pragma unroll
            for (int nt = 0; nt < 2; ++nt)
                #pragma unroll
                for (int pr = 0; pr < 2; ++pr)
                    ob[hh][mt][nt][pr] =
                        (unsigned)f2bf(o[mt][nt][pr * 2]) |
                        ((unsigned)f2bf(o[mt][nt][pr * 2 + 1]) << 16);
    }

    __syncthreads();   // barrier 2: all waves past their last xs read

    // ---- scatter attention output (both heads) into xs as bf16, swizzled
    #pragma unroll
    for (int hh = 0; hh < 2; ++hh) {
        #pragma unroll
        for (int mt = 0; mt < 4; ++mt) {
            #pragma unroll
            for (int nt = 0; nt < 2; ++nt) {
                #pragma unroll
                for (int j = 0; j < 4; ++j) {
                    int tok = mt * 16 + l16 * 4 + j;
                    if (tok < NTOK) {
                        int ch = (wv + 4 * hh) * HD + nt * 16 + l15;
                        int ad = tok * 256 + ((ch & ~7) ^ ((tok & 7) << 3)) + (ch & 7);
                        xs[ad] = (unsigned short)(ob[hh][mt][nt][j >> 1] >> (16 * (j & 1)));
                    }
                }
            }
        }
    }
    __syncthreads();   // barrier 3: ao ready in xs

    // ---- proj: out = ao @ proj_w^T + pb. Wave covers 4 col-tiles (64 cols).
    f32x4 pacc[4][4];
    #pragma unroll
    for (int mt = 0; mt < 4; ++mt)
        #pragma unroll
        for (int u = 0; u < 4; ++u) pacc[mt][u] = (f32x4){0.f,0.f,0.f,0.f};

    int pcol[4];
    float pbv[4];
    #pragma unroll
    for (int u = 0; u < 4; ++u) {
        int bt = wv * 4 + u;
        pcol[u] = (bt >> 3) * 128 + (bt & 7) * 16 + l15;
        pbv[u] = pb[pcol[u]];
    }

    __builtin_amdgcn_s_setprio(1);
    #pragma unroll
    for (int ks2 = 0; ks2 < 8; ++ks2) {
        bf16x8 a[4];
        #pragma unroll
        for (int mt = 0; mt < 4; ++mt)
            a[mt] = *(const bf16x8*)(xs + arow[mt] * 256 +
                      ((ks2 * 32 + l16 * 8) ^ ((arow[mt] & 7) << 3)));
        #pragma unroll
        for (int u = 0; u < 4; ++u) {
            bf16x8 b = *(const bf16x8*)(wpf + (size_t)((wv * 4 + u) * 8 + ks2) * 512 + lane * 8);
            #pragma unroll
            for (int mt = 0; mt < 4; ++mt)
                pacc[mt][u] = __builtin_amdgcn_mfma_f32_16x16x32_bf16(
                    a[mt], b, pacc[mt][u], 0, 0, 0);
        }
    }
    __builtin_amdgcn_s_setprio(0);

    #pragma unroll
    for (int u = 0; u < 4; ++u) {
        #pragma unroll
        for (int mt = 0; mt < 4; ++mt) {
            #pragma unroll
            for (int j = 0; j < 4; ++j) {
                int tok = mt * 16 + l16 * 4 + j;
                if (tok < NTOK)
                    out[((size_t)bw * NTOK + tok) * DIM + pcol[u]] = pacc[mt][u][j] + pbv[u];
            }
        }
    }
}

extern "C" void kernel_launch(void* const* d_in, const int* in_sizes, int n_in,
                              void* d_out, int out_size, void* d_ws, size_t ws_size,
                              hipStream_t stream) {
    const float* x    = (const float*)d_in[0];
    const float* mask = (const float*)d_in[1];
    const float* qkvw = (const float*)d_in[2];
    const float* qkvb = (const float*)d_in[3];
    const float* pw   = (const float*)d_in[4];
    const float* pb   = (const float*)d_in[5];
    const float* bt   = (const float*)d_in[6];
    const int*   ri   = (const int*)d_in[7];
    float* out = (float*)d_out;

    unsigned short* wqf = (unsigned short*)d_ws;
    unsigned short* wpf = wqf + 196608;
    unsigned short* bmf = (unsigned short*)((char*)d_ws + 524288);  // 4 MB

    const int nwin = in_sizes[0] / (NTOK * DIM);      // 4096
    const int total = 262144 + 64 * HEADS * 16 * 256; // 2359296

    k0_prep<<<(total + 255) / 256, 256, 0, stream>>>(qkvw, pw, mask, bt, ri,
                                                     wqf, wpf, bmf, total);
    k1_fused<<<nwin, 256, 0, stream>>>(x, qkvb, pb, wqf, wpf, bmf, out);
}